// Round 5
// baseline (218.085 us; speedup 1.0000x reference)
//
#include <hip/hip_runtime.h>
#include <cstdint>
#include <cstddef>

// dec: [16, 3999, 512] fp32, wgt: [16, 512] fp32, out: [16, 32000] fp32
//   est[f][w] = dot(dec[f], wgt[w]);  out[8g+i] = est[g][i] + est[g-1][8+i]
//
// R11 = R8's coalesced global_load_lds staging with the CORRECT async
// pipeline: raw s_barrier + counted inline-asm s_waitcnt vmcnt(4), so the
// next chunk's staging loads stay in flight across this chunk's compute
// (T3/T4). R8's failure was __syncthreads() = vmcnt(0) drain every chunk
// -> 8 lockstepped HBM-latency exposures (81 us, all pipes idle).
//   R6/R7/R10 post-mortem: direct scattered loads (lane=frame, 2 KB lane
//   stride, 64 distinct lines per VMEM instr) are occupancy- and
//   weight-path-independent at ~45-60 us -> per-CU TA/L1 transaction
//   limit. Only coalescing fixes that; staging moves 1 KB of fully-used
//   contiguous data per instruction.
// LDS: 2 x 16 KB chunk buffers (linear dest as gload_lds requires);
// global source pre-swizzled with the involution u^(frame&7) so the
// compute-side ds_read_b128 (row stride 256 B) is bank-conflict-free.
// 4 waves split over W (4 rows each, full K); weights via wave-uniform
// scalar loads. Reduction buffer overlays xbuf[0], stride 65.

#define NBC     16
#define FRAMES  3999
#define EE      512
#define TOUT    32000
#define NGROUP  4000
#define GPB     63      // output groups per block (64 frame-slots)
#define RSTR    65      // red row stride (pad: 64+1)

__device__ __forceinline__ void gload_lds16(const float* src, float* dst) {
    __builtin_amdgcn_global_load_lds(
        (const __attribute__((address_space(1))) void*)src,
        (__attribute__((address_space(3))) void*)dst,
        16, 0, 0);
}

__global__ __launch_bounds__(256, 4) void decoder_kernel(
    const float* __restrict__ dec,
    const float* __restrict__ wgt,
    float* __restrict__ out)
{
    __shared__ __align__(16) float xbuf[2][64 * 64];  // 2 x 16 KB chunk tiles
    float* red = xbuf[0];                             // ~4 KB overlay after loop

    const int tid   = threadIdx.x;
    const int bc    = blockIdx.x >> 6;   // 0..15
    const int chunk = blockIdx.x & 63;   // 0..63
    const int g0    = chunk * GPB;

    const int s    = tid & 63;                                  // frame slot
    const int lane = tid & 63;
    const int h    = __builtin_amdgcn_readfirstlane(tid >> 6);  // wave id 0..3

    const int f = g0 - 1 + s;
    const float vmask = (f >= 0 && f < FRAMES) ? 1.0f : 0.0f;

    const float* decb = dec + (size_t)bc * FRAMES * EE;

    // staging plan: 1024 float4 units per chunk, 4 per thread.
    // unit l = h*256 + i*64 + lane; frame slot = l>>4;
    // source f4 within frame's 64-float chunk = (l&15) ^ (frame&7) (involution);
    // LDS dest byte = l*16 (linear, as global_load_lds requires).
    const float* srcp[4];
    float*       dstp[4];
    #pragma unroll
    for (int i = 0; i < 4; ++i) {
        const int l  = h * 256 + i * 64 + lane;
        const int fs = l >> 4;                        // frame slot 0..63
        const int us = (l & 15) ^ (fs & 7);           // pre-swizzled source f4
        const int ff = min(max(g0 - 1 + fs, 0), FRAMES - 1);
        srcp[i] = decb + (size_t)ff * EE + us * 4;    // + c*64 per chunk
        dstp[i] = &xbuf[0][0] + (size_t)l * 4;        // + 4096 for buffer 1
    }

    float acc[4] = {0.f, 0.f, 0.f, 0.f};
    const float* wb = wgt + (h * 4) * EE;             // this wave's 4 weight rows

    // ---- prologue: stage chunks 0 and 1 (8 loads in flight per wave) ----
    #pragma unroll
    for (int i = 0; i < 4; ++i) gload_lds16(srcp[i],      dstp[i]);
    #pragma unroll
    for (int i = 0; i < 4; ++i) gload_lds16(srcp[i] + 64, dstp[i] + 4096);

    // ---- main loop: counted vmcnt keeps next chunk's loads in flight ----
    #pragma unroll
    for (int c = 0; c < 8; ++c) {
        if (c < 7) asm volatile("s_waitcnt vmcnt(4)" ::: "memory");
        else       asm volatile("s_waitcnt vmcnt(0)" ::: "memory");
        __builtin_amdgcn_sched_barrier(0);
        __builtin_amdgcn_s_barrier();     // all waves' chunk-c data in LDS

        const float* xb = xbuf[c & 1];
        #pragma unroll
        for (int hf = 0; hf < 2; ++hf) {
            float4 xv[8];
            #pragma unroll
            for (int u8 = 0; u8 < 8; ++u8) {
                const int u = hf * 8 + u8;
                xv[u8] = *(const float4*)(xb + s * 64 + ((4 * u) ^ ((s & 7) << 2)));
            }
            #pragma unroll
            for (int w = 0; w < 4; ++w) {
                const float* wr = wb + w * EE + c * 64 + hf * 32;  // uniform
                #pragma unroll
                for (int u8 = 0; u8 < 8; ++u8) {
                    acc[w] += xv[u8].x * wr[4 * u8 + 0]
                            + xv[u8].y * wr[4 * u8 + 1]
                            + xv[u8].z * wr[4 * u8 + 2]
                            + xv[u8].w * wr[4 * u8 + 3];
                }
            }
        }
        __builtin_amdgcn_sched_barrier(0);
        __builtin_amdgcn_s_barrier();     // all reads of buf[c&1] done
        if (c + 2 < 8) {                  // stage chunk c+2 into the freed buf
            #pragma unroll
            for (int i = 0; i < 4; ++i)
                gload_lds16(srcp[i] + (c + 2) * 64, dstp[i] + (c & 1) * 4096);
        }
    }

    // ---- est[f][w] -> red[w][s] (full-K result; overlays xbuf[0]) ----
    #pragma unroll
    for (int w = 0; w < 4; ++w)
        red[(h * 4 + w) * RSTR + s] = acc[w] * vmask;
    __syncthreads();

    // ---- fused overlap-add: 504 outputs, 256 threads -> 2 iterations ----
    for (int o = tid; o < GPB * 8; o += 256) {
        const int j = o >> 3;            // group offset in block, 0..62
        const int i = o & 7;             // sample within group
        const int g = g0 + j;
        if (g < NGROUP)
            out[(size_t)bc * TOUT + g * 8 + i]
                = red[i * RSTR + (j + 1)]        // est[g][i]
                + red[(8 + i) * RSTR + j];       // est[g-1][8+i]
    }
}

extern "C" void kernel_launch(void* const* d_in, const int* in_sizes, int n_in,
                              void* d_out, int out_size, void* d_ws, size_t ws_size,
                              hipStream_t stream) {
    const float* dec = (const float*)d_in[0];   // [8,2,3999,512] fp32
    const float* wgt = (const float*)d_in[1];   // [16,512] fp32
    float* out = (float*)d_out;                 // [8,2,32000] fp32

    decoder_kernel<<<dim3(1024), dim3(256), 0, stream>>>(dec, wgt, out);
}